// Round 1
// baseline (296.537 us; speedup 1.0000x reference)
//
#include <hip/hip_runtime.h>
#include <hip/hip_bf16.h>

// Problem constants (match reference)
#define NB 128          // graphs
#define NN 512          // nodes per graph
#define NF 128          // feature dim
#define BN (NB*NN)      // 65536 total nodes
#define NE (BN*16)      // 1048576 edges
#define EPG 8192        // edges per graph (N*DEG_AVG)
#define WPR 16          // bitmap words per row (512 bits / 32)
#define ELLW 64         // ELL width (max padded degree)
#define QST 24          // poly w row stride in ushorts (48 B, 16-B aligned)
#define SST 72          // build-kernel ELL staging stride
#define WTS 136         // gemm Wt LDS stride in ushorts (272 B, 16-B aligned)

typedef short sh8 __attribute__((ext_vector_type(8)));
typedef float f32x4 __attribute__((ext_vector_type(4)));

static __device__ __forceinline__ unsigned short f2bf(float f) {
    unsigned u = __float_as_uint(f);
    u += 0x7fffu + ((u >> 16) & 1u);        // round-to-nearest-even
    return (unsigned short)(u >> 16);
}

// acc += bf16_low(pk)  /  acc += bf16_high(pk) via VOP3P dot2:
// D = S0.x*S1.x + S0.y*S1.y + S2 ; products exact (x1.0), +0 exact ->
// bitwise identical to shift+add, at half the instruction count.
#define DOT2LO(acc_, pk_, one_) \
    asm("v_dot2_f32_bf16 %0, %1, %2, %0" : "+v"(acc_) : "v"(pk_), "v"(one_))

// ---------------------------------------------------------------------------
// Fused adjacency + ELL build, one block per graph. LDS bitmap dedup.
// Rows ranked by degree; everything downstream lives in rank space.
// (unchanged)
// ---------------------------------------------------------------------------
__global__ __launch_bounds__(512) void build_ell_fused_kernel(
    const int* __restrict__ src, const int* __restrict__ dst,
    unsigned short* __restrict__ ell, int* __restrict__ ocnt,
    float* __restrict__ dinvr, int* __restrict__ perm)
{
    __shared__ unsigned bm[NN * WPR];   // 32 KB; later reused as ELL staging
    __shared__ int cs[NN];              // degree by row
    __shared__ int rdeg[NN];            // degree by rank
    __shared__ int irank[NN];           // row -> rank
    int g = blockIdx.x;
    int t = threadIdx.x;                // 0..511

    for (int i = t; i < NN * WPR; i += 512) bm[i] = 0u;
    __syncthreads();

    const int4* sg4 = (const int4*)(src + (size_t)g * EPG);
    const int4* dg4 = (const int4*)(dst + (size_t)g * EPG);
    for (int i = t; i < EPG / 4; i += 512) {
        int4 s4 = sg4[i];
        int4 d4 = dg4[i];
        int s, d;
        s = s4.x & (NN - 1); d = d4.x & (NN - 1);
        atomicOr(&bm[s * WPR + (d >> 5)], 1u << (d & 31));
        s = s4.y & (NN - 1); d = d4.y & (NN - 1);
        atomicOr(&bm[s * WPR + (d >> 5)], 1u << (d & 31));
        s = s4.z & (NN - 1); d = d4.z & (NN - 1);
        atomicOr(&bm[s * WPR + (d >> 5)], 1u << (d & 31));
        s = s4.w & (NN - 1); d = d4.w & (NN - 1);
        atomicOr(&bm[s * WPR + (d >> 5)], 1u << (d & 31));
    }
    __syncthreads();

    // extract this thread's row (row == t) into registers
    unsigned rw[WPR];
    #pragma unroll
    for (int w = 0; w < WPR; ++w) rw[w] = bm[t * WPR + w];
    int deg = 0;
    #pragma unroll
    for (int w = 0; w < WPR; ++w) deg += __popc(rw[w]);
    if (deg > ELLW) deg = ELLW;         // defensive
    cs[t] = deg;
    __syncthreads();                    // all bm reads done; cs visible

    // deterministic rank: ascending by (deg, row). LDS reads are broadcasts.
    int rk = 0;
    for (int i = 0; i < NN; ++i) {
        int di_ = cs[i];
        rk += (di_ < deg) || (di_ == deg && i < t);
    }
    rdeg[rk] = deg;
    irank[t] = rk;
    perm[(size_t)g * NN + rk] = t;
    dinvr[(size_t)g * NN + rk] = (deg > 0) ? rsqrtf((float)deg) : 0.0f;
    __syncthreads();

    if (t < NN / 8) {
        // ascending sort: oct max = last element of the oct
        int m = rdeg[t * 8 + 7];
        ocnt[(size_t)g * (NN / 8) + t] = (m + 3) & ~3;
    }

    // ELL staging (rank order, RANK-mapped entries) + coalesced writeout
    unsigned short* els = (unsigned short*)bm;
    for (int qtr = 0; qtr < 4; ++qtr) {
        if ((rk >> 7) == qtr) {
            unsigned short* er = &els[(rk & 127) * SST];
            int c = 0;
            #pragma unroll
            for (int w = 0; w < WPR; ++w) {
                unsigned bits = rw[w];
                while (bits) {
                    int j = __ffs(bits) - 1;
                    bits &= bits - 1;
                    if (c < ELLW) er[c] = (unsigned short)irank[w * 32 + j];
                    ++c;
                }
            }
            if (c > ELLW) c = ELLW;
            for (int p = c; p < ELLW; ++p) er[p] = (unsigned short)NN;
        }
        __syncthreads();
        unsigned short* outb = ell + ((size_t)g * NN + qtr * 128) * ELLW;
        for (int idx = t; idx < 1024; idx += 512) {
            int r2 = idx >> 3, sg2 = idx & 7;
            uint4 v = *(const uint4*)&els[r2 * SST + sg2 * 8];
            *(uint4*)&outb[(size_t)r2 * ELLW + sg2 * 8] = v;
        }
        __syncthreads();
    }
}

// ---------------------------------------------------------------------------
// Fused 3-hop poly conv in RANK space, one block per (graph, feature-EIGHTH).
// grid = 1024 blocks of 512 thr, 26.7 KB LDS -> 4 blocks/CU = 32 waves/CU
// (full occupancy; the previous 4-way feature split capped at 16 waves/CU
// and left the LDS pipe ~50% idle on latency).
// g = bid & 127 so all 8 blocks of a graph share one XCD's L2 for ELL.
// ---------------------------------------------------------------------------
__global__ __launch_bounds__(512, 8) void poly_fused_kernel(
    const float* __restrict__ xin,            // [BN, NF]
    float* __restrict__ accout,               // [BN, NF] rank space
    const unsigned short* __restrict__ ell,   // [BN][ELLW] rank entries
    const int* __restrict__ ocnt,             // [BN/8] padded oct counts
    const float* __restrict__ dinvr,          // [BN] rank-indexed
    const int* __restrict__ perm,             // [BN] rank -> row
    int permuteIn)
{
    extern __shared__ float lds[];
    unsigned short* w = (unsigned short*)lds;        // (NN+1) rows * QST
    float* dsh = lds + ((NN + 1) * QST * 2) / 4;     // NN floats

    int b = blockIdx.x;
    int g = b & 127;                     // graph (same-graph blocks -> same XCD)
    int q = b >> 7;                      // feature eighth (16 feats)
    int t = threadIdx.x;                 // 0..511
    int lane = t & 63;
    int wid  = t >> 6;                   // 0..7
    int slot = lane >> 1;                // 0..31
    int fb   = lane & 1;                 // 0..1 (8 feats each)

    unsigned one_lo = 0x00003F80u;       // bf16x2 (1.0, 0.0)
    unsigned one_hi = 0x3F800000u;       // bf16x2 (0.0, 1.0)

    if (t < NN) dsh[t] = dinvr[(size_t)g * NN + t];
    if (t < QST) w[NN * QST + t] = 0;    // zero sentinel row (bf16 0)

    int rq0 = wid * 64;                  // first rank of this wave
    int rown = rq0 + slot;               // own rank for group x is rown + 32*x

    // input row for each group: perm'd for layer 1, identity (coalesced) else
    int px[2];
    if (permuteIn) {
        const int* pmg = perm + (size_t)g * NN + rown;
        px[0] = pmg[0];
        px[1] = pmg[32];
    } else {
        px[0] = rown;
        px[1] = rown + 32;
    }

    const float* xg = xin + (size_t)g * NN * NF + q * 16 + fb * 8;

    float acc[2][8];
    #pragma unroll
    for (int x = 0; x < 2; ++x) {
        int row = px[x];
        float4 a0 = *(const float4*)&xg[(size_t)row * NF];
        float4 a1 = *(const float4*)&xg[(size_t)row * NF + 4];
        acc[x][0] = a0.x; acc[x][1] = a0.y; acc[x][2] = a0.z; acc[x][3] = a0.w;
        acc[x][4] = a1.x; acc[x][5] = a1.y; acc[x][6] = a1.z; acc[x][7] = a1.w;
    }

    // per-group counts: max of the group's four oct counts (wave-uniform;
    // ranks are degree-ascending so the last oct dominates, but take max
    // defensively — these are scalar-cached loads)
    const int* oc = ocnt + (size_t)g * (NN / 8) + wid * 8;
    int co[2];
    #pragma unroll
    for (int x = 0; x < 2; ++x) {
        int m0 = max(oc[4 * x], oc[4 * x + 1]);
        int m1 = max(oc[4 * x + 2], oc[4 * x + 3]);
        co[x] = __builtin_amdgcn_readfirstlane(max(m0, m1));
    }

    __syncthreads();                     // dsh + sentinel ready

    #pragma unroll
    for (int x = 0; x < 2; ++x) {
        int rr = rown + 32 * x;          // rank position
        float di = dsh[rr];
        unsigned pk[4];
        #pragma unroll
        for (int k = 0; k < 4; ++k) {
            unsigned lo = (unsigned)f2bf(di * acc[x][2 * k]);
            unsigned hi = (unsigned)f2bf(di * acc[x][2 * k + 1]);
            pk[k] = lo | (hi << 16);
        }
        *(uint4*)&w[rr * QST + fb * 8] = make_uint4(pk[0], pk[1], pk[2], pk[3]);
    }
    __syncthreads();                     // w init ready

    const unsigned short* elbase = ell + ((size_t)g * NN + rown) * ELLW;

    for (int hop = 0; hop < 3; ++hop) {
        float stage[2][8];
        ushort4 nq = *(const ushort4*)elbase;   // group 0, batch 0
        #pragma unroll
        for (int x = 0; x < 2; ++x) {
            const unsigned short* el = elbase + (size_t)(32 * x) * ELLW;
            int cnt = co[x];
            ushort4 cur = nq;
            if (x < 1)                   // prefetch next group's first batch
                nq = *(const ushort4*)(elbase + (size_t)32 * ELLW);
            float s[8];
            #pragma unroll
            for (int k = 0; k < 8; ++k) s[k] = 0.0f;
            for (int p = 0; p < cnt; p += 4) {
                ushort4 nxt = cur;
                if (p + 4 < cnt) nxt = *(const ushort4*)(el + p + 4);
                uint4 v0 = *(const uint4*)&w[(int)cur.x * QST + fb * 8];
                uint4 v1 = *(const uint4*)&w[(int)cur.y * QST + fb * 8];
                uint4 v2 = *(const uint4*)&w[(int)cur.z * QST + fb * 8];
                uint4 v3 = *(const uint4*)&w[(int)cur.w * QST + fb * 8];
                unsigned d[4][4] = {{v0.x, v0.y, v0.z, v0.w},
                                    {v1.x, v1.y, v1.z, v1.w},
                                    {v2.x, v2.y, v2.z, v2.w},
                                    {v3.x, v3.y, v3.z, v3.w}};
                #pragma unroll
                for (int n = 0; n < 4; ++n) {
                    #pragma unroll
                    for (int k = 0; k < 4; ++k) {
                        DOT2LO(s[2 * k],     d[n][k], one_lo);
                        DOT2LO(s[2 * k + 1], d[n][k], one_hi);
                    }
                }
                cur = nxt;
            }
            #pragma unroll
            for (int k = 0; k < 8; ++k) stage[x][k] = s[k];
        }
        __syncthreads();                 // all reads of old w done
        #pragma unroll
        for (int x = 0; x < 2; ++x) {
            int rr = rown + 32 * x;
            float di = dsh[rr];
            unsigned pk[4];
            #pragma unroll
            for (int k = 0; k < 4; ++k) {
                float zlo = di * stage[x][2 * k];
                float zhi = di * stage[x][2 * k + 1];
                acc[x][2 * k]     += zlo;
                acc[x][2 * k + 1] += zhi;
                unsigned lo = (unsigned)f2bf(di * zlo);
                unsigned hi = (unsigned)f2bf(di * zhi);
                pk[k] = lo | (hi << 16);
            }
            *(uint4*)&w[rr * QST + fb * 8] = make_uint4(pk[0], pk[1], pk[2], pk[3]);
        }
        __syncthreads();                 // new w visible
    }

    // coalesced write at rank positions
    float* og = accout + (size_t)g * NN * NF + q * 16 + fb * 8;
    #pragma unroll
    for (int x = 0; x < 2; ++x) {
        int rr = rown + 32 * x;
        *(float4*)&og[(size_t)rr * NF] =
            make_float4(acc[x][0], acc[x][1], acc[x][2], acc[x][3]);
        *(float4*)&og[(size_t)rr * NF + 4] =
            make_float4(acc[x][4], acc[x][5], acc[x][6], acc[x][7]);
    }
}

// ---------------------------------------------------------------------------
// MFMA bf16 GEMM: Y[65536,128] = relu(bf16(X) @ bf16(W) + b), optional fused
// deterministic mean-pool partials. (unchanged)
// ---------------------------------------------------------------------------
__global__ __launch_bounds__(256, 2) void gemm_bias_relu_kernel(
    const float* __restrict__ X, const float* __restrict__ W,
    const float* __restrict__ b, float* __restrict__ Y,
    float* __restrict__ partial, int fuse)
{
    __shared__ __align__(16) unsigned short Wt[NF * WTS];  // [n][k] bf16
    __shared__ float part[4 * NF];

    int t = threadIdx.x;

    // stage Wt = W^T in bf16
    for (int i = t; i < NF * NF / 4; i += 256) {
        int k = i >> 5;                 // W row
        int n4 = (i & 31) * 4;          // W col group
        float4 wv = ((const float4*)W)[i];
        Wt[(n4 + 0) * WTS + k] = f2bf(wv.x);
        Wt[(n4 + 1) * WTS + k] = f2bf(wv.y);
        Wt[(n4 + 2) * WTS + k] = f2bf(wv.z);
        Wt[(n4 + 3) * WTS + k] = f2bf(wv.w);
    }
    __syncthreads();

    int lane = t & 63;
    int wid  = t >> 6;                  // 0..3
    int quad = lane >> 4;               // 0..3
    int l16  = lane & 15;
    int rowA0 = blockIdx.x * 128 + wid * 32;

    // A fragments: af[m][kk], m in {0,1} (row halves), kk = K-step
    union { unsigned short u[8]; sh8 v; } af[2][4];
    #pragma unroll
    for (int m = 0; m < 2; ++m) {
        int r = rowA0 + m * 16 + l16;
        const float* xr = X + (size_t)r * NF + quad * 8;
        #pragma unroll
        for (int kk = 0; kk < 4; ++kk) {
            float4 x0 = *(const float4*)(xr + kk * 32);
            float4 x1 = *(const float4*)(xr + kk * 32 + 4);
            af[m][kk].u[0] = f2bf(x0.x); af[m][kk].u[1] = f2bf(x0.y);
            af[m][kk].u[2] = f2bf(x0.z); af[m][kk].u[3] = f2bf(x0.w);
            af[m][kk].u[4] = f2bf(x1.x); af[m][kk].u[5] = f2bf(x1.y);
            af[m][kk].u[6] = f2bf(x1.z); af[m][kk].u[7] = f2bf(x1.w);
        }
    }

    f32x4 acc[2][8];
    #pragma unroll
    for (int m = 0; m < 2; ++m)
        #pragma unroll
        for (int c = 0; c < 8; ++c) acc[m][c] = (f32x4){0.f, 0.f, 0.f, 0.f};

    #pragma unroll
    for (int c = 0; c < 8; ++c) {
        const unsigned short* wb = &Wt[(c * 16 + l16) * WTS + quad * 8];
        #pragma unroll
        for (int kk = 0; kk < 4; ++kk) {
            union { uint4 q; sh8 v; } bf_;
            bf_.q = *(const uint4*)(wb + kk * 32);
            acc[0][c] = __builtin_amdgcn_mfma_f32_16x16x32_bf16(
                af[0][kk].v, bf_.v, acc[0][c], 0, 0, 0);
            acc[1][c] = __builtin_amdgcn_mfma_f32_16x16x32_bf16(
                af[1][kk].v, bf_.v, acc[1][c], 0, 0, 0);
        }
    }

    float psum[8];
    #pragma unroll
    for (int c = 0; c < 8; ++c) psum[c] = 0.0f;

    #pragma unroll
    for (int c = 0; c < 8; ++c) {
        int col = c * 16 + l16;
        float bias = b[col];
        #pragma unroll
        for (int m = 0; m < 2; ++m) {
            #pragma unroll
            for (int reg = 0; reg < 4; ++reg) {
                int r = rowA0 + m * 16 + quad * 4 + reg;
                float v = fmaxf(acc[m][c][reg] + bias, 0.0f);
                Y[(size_t)r * NF + col] = v;
                psum[c] += v;
            }
        }
    }

    if (fuse) {
        // deterministic cross-quad reduction, then cross-wave LDS tree
        #pragma unroll
        for (int c = 0; c < 8; ++c) {
            float v = psum[c];
            v += __shfl_xor(v, 16);
            v += __shfl_xor(v, 32);
            if (lane < 16) part[wid * NF + c * 16 + lane] = v;
        }
        __syncthreads();
        if (t < NF) {
            float s = part[t] + part[NF + t] + part[2 * NF + t]
                    + part[3 * NF + t];
            partial[(size_t)blockIdx.x * NF + t] = s;
        }
    }
}

// ---------------------------------------------------------------------------
// Readout: per graph, mean-pool from gemm2 partials (4 blocks/graph) + MLP.
// ---------------------------------------------------------------------------
__global__ __launch_bounds__(128) void readout_kernel(
    const float* __restrict__ partial,   // [BN/128][NF]
    const float* __restrict__ Wr1, const float* __restrict__ br1,
    const float* __restrict__ Wr2, const float* __restrict__ br2,
    float* __restrict__ out)
{
    __shared__ float hsh[NF];
    __shared__ float r1[64];

    int g = blockIdx.x;
    int t = threadIdx.x;

    const float* pg = partial + (size_t)g * 4 * NF;
    float s = 0.0f;
    #pragma unroll
    for (int j = 0; j < 4; ++j) s += pg[j * NF + t];
    hsh[t] = s * (1.0f / (float)NN);
    __syncthreads();

    if (t < 64) {
        float a = br1[t];
        #pragma unroll 8
        for (int k = 0; k < NF; ++k) a += hsh[k] * Wr1[k * 64 + t];
        r1[t] = fmaxf(a, 0.0f);
    }
    __syncthreads();

    if (t < 64) {
        float v = r1[t] * Wr2[t];
        #pragma unroll
        for (int off = 32; off; off >>= 1) v += __shfl_down(v, off);
        if (t == 0) out[g] = v + br2[0];
    }
}

// ---------------------------------------------------------------------------
extern "C" void kernel_launch(void* const* d_in, const int* in_sizes, int n_in,
                              void* d_out, int out_size, void* d_ws, size_t ws_size,
                              hipStream_t stream)
{
    const float* X    = (const float*)d_in[0];
    // d_in[1] = batch (unused; nodes already grouped per graph)
    const int*   ei   = (const int*)d_in[2];
    const float* W1   = (const float*)d_in[3];
    const float* b1   = (const float*)d_in[4];
    const float* W2   = (const float*)d_in[5];
    const float* b2   = (const float*)d_in[6];
    const float* Wr1  = (const float*)d_in[7];
    const float* br1  = (const float*)d_in[8];
    const float* Wr2  = (const float*)d_in[9];
    const float* br2  = (const float*)d_in[10];
    float* out = (float*)d_out;

    const int* src = ei;
    const int* dst = ei + NE;

    // workspace layout
    char* ws = (char*)d_ws;
    float*          dinvr   = (float*)(ws);                          // 256 KB
    int*            ocnt    = (int*)(ws + (size_t)256 * 1024);       // 32 KB
    int*            perm    = (int*)(ws + (size_t)512 * 1024);       // 256 KB
    float*          partial = (float*)(ws + (size_t)768 * 1024);     // 256 KB
    unsigned short* ell     = (unsigned short*)(ws + (size_t)1024 * 1024); // 8 MB
    float*          buf0    = (float*)(ws + (size_t)16384 * 1024);   // 32 MB
    float*          buf1    = (float*)(ws + (size_t)49152 * 1024);   // 32 MB

    // fused adjacency+ELL build; rank-space outputs
    build_ell_fused_kernel<<<NB, 512, 0, stream>>>(src, dst, ell, ocnt, dinvr,
                                                   perm);

    // bf16 w rows (513 * 48 B) + dsh (512 floats) = 26,672 B
    const size_t LDSSZ = (size_t)(NN + 1) * QST * 2 + NN * 4;

    // ---- Layer 1 (X gathered via perm into rank space)
    poly_fused_kernel<<<NB * 8, 512, LDSSZ, stream>>>(X, buf0, ell, ocnt,
                                                      dinvr, perm, 1);
    gemm_bias_relu_kernel<<<BN / 128, 256, 0, stream>>>(buf0, W1, b1, buf1,
                                                        partial, 0);

    // ---- Layer 2 (all rank space, fully coalesced)
    poly_fused_kernel<<<NB * 8, 512, LDSSZ, stream>>>(buf1, buf0, ell, ocnt,
                                                      dinvr, perm, 0);
    gemm_bias_relu_kernel<<<BN / 128, 256, 0, stream>>>(buf0, W2, b2, buf1,
                                                        partial, 1);

    // ---- Readout from partials
    readout_kernel<<<NB, 128, 0, stream>>>(partial, Wr1, br1, Wr2, br2, out);
}

// Round 2
// 257.251 us; speedup vs baseline: 1.1527x; 1.1527x over previous
//
#include <hip/hip_runtime.h>
#include <hip/hip_bf16.h>

// Problem constants (match reference)
#define NB 128          // graphs
#define NN 512          // nodes per graph
#define NF 128          // feature dim
#define BN (NB*NN)      // 65536 total nodes
#define NE (BN*16)      // 1048576 edges
#define EPG 8192        // edges per graph (N*DEG_AVG)
#define WPR 16          // bitmap words per row (512 bits / 32)
#define ELLW 64         // ELL width (max padded degree)
#define QST 24          // poly w row stride in ushorts (48 B, 16-B aligned)
#define SST 72          // build-kernel ELL staging stride
#define WTS 136         // gemm Wt LDS stride in ushorts (272 B, 16-B aligned)

typedef short sh8 __attribute__((ext_vector_type(8)));
typedef float f32x4 __attribute__((ext_vector_type(4)));

static __device__ __forceinline__ unsigned short f2bf(float f) {
    unsigned u = __float_as_uint(f);
    u += 0x7fffu + ((u >> 16) & 1u);        // round-to-nearest-even
    return (unsigned short)(u >> 16);
}

// acc += bf16_low(pk)  /  acc += bf16_high(pk) via VOP3P dot2:
// D = S0.x*S1.x + S0.y*S1.y + S2 ; products exact (x1.0), +0 exact ->
// bitwise identical to shift+add, at half the instruction count.
#define DOT2LO(acc_, pk_, one_) \
    asm("v_dot2_f32_bf16 %0, %1, %2, %0" : "+v"(acc_) : "v"(pk_), "v"(one_))

// ---------------------------------------------------------------------------
// Fused adjacency + ELL build, one block per graph. LDS bitmap dedup.
// Rows ranked by degree; everything downstream lives in rank space.
// (unchanged)
// ---------------------------------------------------------------------------
__global__ __launch_bounds__(512) void build_ell_fused_kernel(
    const int* __restrict__ src, const int* __restrict__ dst,
    unsigned short* __restrict__ ell, int* __restrict__ ocnt,
    float* __restrict__ dinvr, int* __restrict__ perm)
{
    __shared__ unsigned bm[NN * WPR];   // 32 KB; later reused as ELL staging
    __shared__ int cs[NN];              // degree by row
    __shared__ int rdeg[NN];            // degree by rank
    __shared__ int irank[NN];           // row -> rank
    int g = blockIdx.x;
    int t = threadIdx.x;                // 0..511

    for (int i = t; i < NN * WPR; i += 512) bm[i] = 0u;
    __syncthreads();

    const int4* sg4 = (const int4*)(src + (size_t)g * EPG);
    const int4* dg4 = (const int4*)(dst + (size_t)g * EPG);
    for (int i = t; i < EPG / 4; i += 512) {
        int4 s4 = sg4[i];
        int4 d4 = dg4[i];
        int s, d;
        s = s4.x & (NN - 1); d = d4.x & (NN - 1);
        atomicOr(&bm[s * WPR + (d >> 5)], 1u << (d & 31));
        s = s4.y & (NN - 1); d = d4.y & (NN - 1);
        atomicOr(&bm[s * WPR + (d >> 5)], 1u << (d & 31));
        s = s4.z & (NN - 1); d = d4.z & (NN - 1);
        atomicOr(&bm[s * WPR + (d >> 5)], 1u << (d & 31));
        s = s4.w & (NN - 1); d = d4.w & (NN - 1);
        atomicOr(&bm[s * WPR + (d >> 5)], 1u << (d & 31));
    }
    __syncthreads();

    // extract this thread's row (row == t) into registers
    unsigned rw[WPR];
    #pragma unroll
    for (int w = 0; w < WPR; ++w) rw[w] = bm[t * WPR + w];
    int deg = 0;
    #pragma unroll
    for (int w = 0; w < WPR; ++w) deg += __popc(rw[w]);
    if (deg > ELLW) deg = ELLW;         // defensive
    cs[t] = deg;
    __syncthreads();                    // all bm reads done; cs visible

    // deterministic rank: ascending by (deg, row). LDS reads are broadcasts.
    int rk = 0;
    for (int i = 0; i < NN; ++i) {
        int di_ = cs[i];
        rk += (di_ < deg) || (di_ == deg && i < t);
    }
    rdeg[rk] = deg;
    irank[t] = rk;
    perm[(size_t)g * NN + rk] = t;
    dinvr[(size_t)g * NN + rk] = (deg > 0) ? rsqrtf((float)deg) : 0.0f;
    __syncthreads();

    if (t < NN / 8) {
        // ascending sort: oct max = last element of the oct
        int m = rdeg[t * 8 + 7];
        ocnt[(size_t)g * (NN / 8) + t] = (m + 3) & ~3;
    }

    // ELL staging (rank order, RANK-mapped entries) + coalesced writeout
    unsigned short* els = (unsigned short*)bm;
    for (int qtr = 0; qtr < 4; ++qtr) {
        if ((rk >> 7) == qtr) {
            unsigned short* er = &els[(rk & 127) * SST];
            int c = 0;
            #pragma unroll
            for (int w = 0; w < WPR; ++w) {
                unsigned bits = rw[w];
                while (bits) {
                    int j = __ffs(bits) - 1;
                    bits &= bits - 1;
                    if (c < ELLW) er[c] = (unsigned short)irank[w * 32 + j];
                    ++c;
                }
            }
            if (c > ELLW) c = ELLW;
            for (int p = c; p < ELLW; ++p) er[p] = (unsigned short)NN;
        }
        __syncthreads();
        unsigned short* outb = ell + ((size_t)g * NN + qtr * 128) * ELLW;
        for (int idx = t; idx < 1024; idx += 512) {
            int r2 = idx >> 3, sg2 = idx & 7;
            uint4 v = *(const uint4*)&els[r2 * SST + sg2 * 8];
            *(uint4*)&outb[(size_t)r2 * ELLW + sg2 * 8] = v;
        }
        __syncthreads();
    }
}

// ---------------------------------------------------------------------------
// Fused 3-hop poly conv in RANK space, one block per (graph, feature-EIGHTH).
// grid = 1024 blocks of 512 thr, 26.7 KB LDS -> 4 blocks/CU = 32 waves/CU.
// __launch_bounds__(512, 4): R1 showed that min-waves=8 (VGPR cap 64) makes
// the allocator squeeze to 32 VGPR + scratch spill (WRITE_SIZE 33->107 MB,
// 169us first dispatch). Cap 128 lets natural pressure (~50) land under 64,
// which by itself permits 8 waves/SIMD — occupancy without spill.
// g = bid & 127 so all 8 blocks of a graph share one XCD's L2 for ELL.
// ---------------------------------------------------------------------------
__global__ __launch_bounds__(512, 4) void poly_fused_kernel(
    const float* __restrict__ xin,            // [BN, NF]
    float* __restrict__ accout,               // [BN, NF] rank space
    const unsigned short* __restrict__ ell,   // [BN][ELLW] rank entries
    const int* __restrict__ ocnt,             // [BN/8] padded oct counts
    const float* __restrict__ dinvr,          // [BN] rank-indexed
    const int* __restrict__ perm,             // [BN] rank -> row
    int permuteIn)
{
    extern __shared__ float lds[];
    unsigned short* w = (unsigned short*)lds;        // (NN+1) rows * QST
    float* dsh = lds + ((NN + 1) * QST * 2) / 4;     // NN floats

    int b = blockIdx.x;
    int g = b & 127;                     // graph (same-graph blocks -> same XCD)
    int q = b >> 7;                      // feature eighth (16 feats)
    int t = threadIdx.x;                 // 0..511
    int lane = t & 63;
    int wid  = t >> 6;                   // 0..7
    int slot = lane >> 1;                // 0..31
    int fb   = lane & 1;                 // 0..1 (8 feats each)

    unsigned one_lo = 0x00003F80u;       // bf16x2 (1.0, 0.0)
    unsigned one_hi = 0x3F800000u;       // bf16x2 (0.0, 1.0)

    if (t < NN) dsh[t] = dinvr[(size_t)g * NN + t];
    if (t < QST) w[NN * QST + t] = 0;    // zero sentinel row (bf16 0)

    int rq0 = wid * 64;                  // first rank of this wave
    int rown = rq0 + slot;               // own rank for group x is rown + 32*x

    // input row for each group: perm'd for layer 1, identity (coalesced) else
    int px[2];
    if (permuteIn) {
        const int* pmg = perm + (size_t)g * NN + rown;
        px[0] = pmg[0];
        px[1] = pmg[32];
    } else {
        px[0] = rown;
        px[1] = rown + 32;
    }

    const float* xg = xin + (size_t)g * NN * NF + q * 16 + fb * 8;

    float acc[2][8];
    #pragma unroll
    for (int x = 0; x < 2; ++x) {
        int row = px[x];
        float4 a0 = *(const float4*)&xg[(size_t)row * NF];
        float4 a1 = *(const float4*)&xg[(size_t)row * NF + 4];
        acc[x][0] = a0.x; acc[x][1] = a0.y; acc[x][2] = a0.z; acc[x][3] = a0.w;
        acc[x][4] = a1.x; acc[x][5] = a1.y; acc[x][6] = a1.z; acc[x][7] = a1.w;
    }

    // per-group counts: max of the group's four oct counts (wave-uniform;
    // ranks are degree-ascending so the last oct dominates, but take max
    // defensively — these are scalar-cached loads)
    const int* oc = ocnt + (size_t)g * (NN / 8) + wid * 8;
    int co[2];
    #pragma unroll
    for (int x = 0; x < 2; ++x) {
        int m0 = max(oc[4 * x], oc[4 * x + 1]);
        int m1 = max(oc[4 * x + 2], oc[4 * x + 3]);
        co[x] = __builtin_amdgcn_readfirstlane(max(m0, m1));
    }

    __syncthreads();                     // dsh + sentinel ready

    #pragma unroll
    for (int x = 0; x < 2; ++x) {
        int rr = rown + 32 * x;          // rank position
        float di = dsh[rr];
        unsigned pk[4];
        #pragma unroll
        for (int k = 0; k < 4; ++k) {
            unsigned lo = (unsigned)f2bf(di * acc[x][2 * k]);
            unsigned hi = (unsigned)f2bf(di * acc[x][2 * k + 1]);
            pk[k] = lo | (hi << 16);
        }
        *(uint4*)&w[rr * QST + fb * 8] = make_uint4(pk[0], pk[1], pk[2], pk[3]);
    }
    __syncthreads();                     // w init ready

    const unsigned short* elbase = ell + ((size_t)g * NN + rown) * ELLW;

    for (int hop = 0; hop < 3; ++hop) {
        float stage[2][8];
        ushort4 nq = *(const ushort4*)elbase;   // group 0, batch 0
        #pragma unroll
        for (int x = 0; x < 2; ++x) {
            const unsigned short* el = elbase + (size_t)(32 * x) * ELLW;
            int cnt = co[x];
            ushort4 cur = nq;
            if (x < 1)                   // prefetch next group's first batch
                nq = *(const ushort4*)(elbase + (size_t)32 * ELLW);
            float s[8];
            #pragma unroll
            for (int k = 0; k < 8; ++k) s[k] = 0.0f;
            for (int p = 0; p < cnt; p += 4) {
                ushort4 nxt = cur;
                if (p + 4 < cnt) nxt = *(const ushort4*)(el + p + 4);
                uint4 v0 = *(const uint4*)&w[(int)cur.x * QST + fb * 8];
                uint4 v1 = *(const uint4*)&w[(int)cur.y * QST + fb * 8];
                uint4 v2 = *(const uint4*)&w[(int)cur.z * QST + fb * 8];
                uint4 v3 = *(const uint4*)&w[(int)cur.w * QST + fb * 8];
                unsigned d[4][4] = {{v0.x, v0.y, v0.z, v0.w},
                                    {v1.x, v1.y, v1.z, v1.w},
                                    {v2.x, v2.y, v2.z, v2.w},
                                    {v3.x, v3.y, v3.z, v3.w}};
                #pragma unroll
                for (int n = 0; n < 4; ++n) {
                    #pragma unroll
                    for (int k = 0; k < 4; ++k) {
                        DOT2LO(s[2 * k],     d[n][k], one_lo);
                        DOT2LO(s[2 * k + 1], d[n][k], one_hi);
                    }
                }
                cur = nxt;
            }
            #pragma unroll
            for (int k = 0; k < 8; ++k) stage[x][k] = s[k];
        }
        __syncthreads();                 // all reads of old w done
        #pragma unroll
        for (int x = 0; x < 2; ++x) {
            int rr = rown + 32 * x;
            float di = dsh[rr];
            unsigned pk[4];
            #pragma unroll
            for (int k = 0; k < 4; ++k) {
                float zlo = di * stage[x][2 * k];
                float zhi = di * stage[x][2 * k + 1];
                acc[x][2 * k]     += zlo;
                acc[x][2 * k + 1] += zhi;
                unsigned lo = (unsigned)f2bf(di * zlo);
                unsigned hi = (unsigned)f2bf(di * zhi);
                pk[k] = lo | (hi << 16);
            }
            *(uint4*)&w[rr * QST + fb * 8] = make_uint4(pk[0], pk[1], pk[2], pk[3]);
        }
        __syncthreads();                 // new w visible
    }

    // coalesced write at rank positions
    float* og = accout + (size_t)g * NN * NF + q * 16 + fb * 8;
    #pragma unroll
    for (int x = 0; x < 2; ++x) {
        int rr = rown + 32 * x;
        *(float4*)&og[(size_t)rr * NF] =
            make_float4(acc[x][0], acc[x][1], acc[x][2], acc[x][3]);
        *(float4*)&og[(size_t)rr * NF + 4] =
            make_float4(acc[x][4], acc[x][5], acc[x][6], acc[x][7]);
    }
}

// ---------------------------------------------------------------------------
// MFMA bf16 GEMM: Y[65536,128] = relu(bf16(X) @ bf16(W) + b), optional fused
// deterministic mean-pool partials. (unchanged)
// ---------------------------------------------------------------------------
__global__ __launch_bounds__(256, 2) void gemm_bias_relu_kernel(
    const float* __restrict__ X, const float* __restrict__ W,
    const float* __restrict__ b, float* __restrict__ Y,
    float* __restrict__ partial, int fuse)
{
    __shared__ __align__(16) unsigned short Wt[NF * WTS];  // [n][k] bf16
    __shared__ float part[4 * NF];

    int t = threadIdx.x;

    // stage Wt = W^T in bf16
    for (int i = t; i < NF * NF / 4; i += 256) {
        int k = i >> 5;                 // W row
        int n4 = (i & 31) * 4;          // W col group
        float4 wv = ((const float4*)W)[i];
        Wt[(n4 + 0) * WTS + k] = f2bf(wv.x);
        Wt[(n4 + 1) * WTS + k] = f2bf(wv.y);
        Wt[(n4 + 2) * WTS + k] = f2bf(wv.z);
        Wt[(n4 + 3) * WTS + k] = f2bf(wv.w);
    }
    __syncthreads();

    int lane = t & 63;
    int wid  = t >> 6;                  // 0..3
    int quad = lane >> 4;               // 0..3
    int l16  = lane & 15;
    int rowA0 = blockIdx.x * 128 + wid * 32;

    // A fragments: af[m][kk], m in {0,1} (row halves), kk = K-step
    union { unsigned short u[8]; sh8 v; } af[2][4];
    #pragma unroll
    for (int m = 0; m < 2; ++m) {
        int r = rowA0 + m * 16 + l16;
        const float* xr = X + (size_t)r * NF + quad * 8;
        #pragma unroll
        for (int kk = 0; kk < 4; ++kk) {
            float4 x0 = *(const float4*)(xr + kk * 32);
            float4 x1 = *(const float4*)(xr + kk * 32 + 4);
            af[m][kk].u[0] = f2bf(x0.x); af[m][kk].u[1] = f2bf(x0.y);
            af[m][kk].u[2] = f2bf(x0.z); af[m][kk].u[3] = f2bf(x0.w);
            af[m][kk].u[4] = f2bf(x1.x); af[m][kk].u[5] = f2bf(x1.y);
            af[m][kk].u[6] = f2bf(x1.z); af[m][kk].u[7] = f2bf(x1.w);
        }
    }

    f32x4 acc[2][8];
    #pragma unroll
    for (int m = 0; m < 2; ++m)
        #pragma unroll
        for (int c = 0; c < 8; ++c) acc[m][c] = (f32x4){0.f, 0.f, 0.f, 0.f};

    #pragma unroll
    for (int c = 0; c < 8; ++c) {
        const unsigned short* wb = &Wt[(c * 16 + l16) * WTS + quad * 8];
        #pragma unroll
        for (int kk = 0; kk < 4; ++kk) {
            union { uint4 q; sh8 v; } bf_;
            bf_.q = *(const uint4*)(wb + kk * 32);
            acc[0][c] = __builtin_amdgcn_mfma_f32_16x16x32_bf16(
                af[0][kk].v, bf_.v, acc[0][c], 0, 0, 0);
            acc[1][c] = __builtin_amdgcn_mfma_f32_16x16x32_bf16(
                af[1][kk].v, bf_.v, acc[1][c], 0, 0, 0);
        }
    }

    float psum[8];
    #pragma unroll
    for (int c = 0; c < 8; ++c) psum[c] = 0.0f;

    #pragma unroll
    for (int c = 0; c < 8; ++c) {
        int col = c * 16 + l16;
        float bias = b[col];
        #pragma unroll
        for (int m = 0; m < 2; ++m) {
            #pragma unroll
            for (int reg = 0; reg < 4; ++reg) {
                int r = rowA0 + m * 16 + quad * 4 + reg;
                float v = fmaxf(acc[m][c][reg] + bias, 0.0f);
                Y[(size_t)r * NF + col] = v;
                psum[c] += v;
            }
        }
    }

    if (fuse) {
        // deterministic cross-quad reduction, then cross-wave LDS tree
        #pragma unroll
        for (int c = 0; c < 8; ++c) {
            float v = psum[c];
            v += __shfl_xor(v, 16);
            v += __shfl_xor(v, 32);
            if (lane < 16) part[wid * NF + c * 16 + lane] = v;
        }
        __syncthreads();
        if (t < NF) {
            float s = part[t] + part[NF + t] + part[2 * NF + t]
                    + part[3 * NF + t];
            partial[(size_t)blockIdx.x * NF + t] = s;
        }
    }
}

// ---------------------------------------------------------------------------
// Readout: per graph, mean-pool from gemm2 partials (4 blocks/graph) + MLP.
// ---------------------------------------------------------------------------
__global__ __launch_bounds__(128) void readout_kernel(
    const float* __restrict__ partial,   // [BN/128][NF]
    const float* __restrict__ Wr1, const float* __restrict__ br1,
    const float* __restrict__ Wr2, const float* __restrict__ br2,
    float* __restrict__ out)
{
    __shared__ float hsh[NF];
    __shared__ float r1[64];

    int g = blockIdx.x;
    int t = threadIdx.x;

    const float* pg = partial + (size_t)g * 4 * NF;
    float s = 0.0f;
    #pragma unroll
    for (int j = 0; j < 4; ++j) s += pg[j * NF + t];
    hsh[t] = s * (1.0f / (float)NN);
    __syncthreads();

    if (t < 64) {
        float a = br1[t];
        #pragma unroll 8
        for (int k = 0; k < NF; ++k) a += hsh[k] * Wr1[k * 64 + t];
        r1[t] = fmaxf(a, 0.0f);
    }
    __syncthreads();

    if (t < 64) {
        float v = r1[t] * Wr2[t];
        #pragma unroll
        for (int off = 32; off; off >>= 1) v += __shfl_down(v, off);
        if (t == 0) out[g] = v + br2[0];
    }
}

// ---------------------------------------------------------------------------
extern "C" void kernel_launch(void* const* d_in, const int* in_sizes, int n_in,
                              void* d_out, int out_size, void* d_ws, size_t ws_size,
                              hipStream_t stream)
{
    const float* X    = (const float*)d_in[0];
    // d_in[1] = batch (unused; nodes already grouped per graph)
    const int*   ei   = (const int*)d_in[2];
    const float* W1   = (const float*)d_in[3];
    const float* b1   = (const float*)d_in[4];
    const float* W2   = (const float*)d_in[5];
    const float* b2   = (const float*)d_in[6];
    const float* Wr1  = (const float*)d_in[7];
    const float* br1  = (const float*)d_in[8];
    const float* Wr2  = (const float*)d_in[9];
    const float* br2  = (const float*)d_in[10];
    float* out = (float*)d_out;

    const int* src = ei;
    const int* dst = ei + NE;

    // workspace layout
    char* ws = (char*)d_ws;
    float*          dinvr   = (float*)(ws);                          // 256 KB
    int*            ocnt    = (int*)(ws + (size_t)256 * 1024);       // 32 KB
    int*            perm    = (int*)(ws + (size_t)512 * 1024);       // 256 KB
    float*          partial = (float*)(ws + (size_t)768 * 1024);     // 256 KB
    unsigned short* ell     = (unsigned short*)(ws + (size_t)1024 * 1024); // 8 MB
    float*          buf0    = (float*)(ws + (size_t)16384 * 1024);   // 32 MB
    float*          buf1    = (float*)(ws + (size_t)49152 * 1024);   // 32 MB

    // fused adjacency+ELL build; rank-space outputs
    build_ell_fused_kernel<<<NB, 512, 0, stream>>>(src, dst, ell, ocnt, dinvr,
                                                   perm);

    // bf16 w rows (513 * 48 B) + dsh (512 floats) = 26,672 B
    const size_t LDSSZ = (size_t)(NN + 1) * QST * 2 + NN * 4;

    // ---- Layer 1 (X gathered via perm into rank space)
    poly_fused_kernel<<<NB * 8, 512, LDSSZ, stream>>>(X, buf0, ell, ocnt,
                                                      dinvr, perm, 1);
    gemm_bias_relu_kernel<<<BN / 128, 256, 0, stream>>>(buf0, W1, b1, buf1,
                                                        partial, 0);

    // ---- Layer 2 (all rank space, fully coalesced)
    poly_fused_kernel<<<NB * 8, 512, LDSSZ, stream>>>(buf1, buf0, ell, ocnt,
                                                      dinvr, perm, 0);
    gemm_bias_relu_kernel<<<BN / 128, 256, 0, stream>>>(buf0, W2, b2, buf1,
                                                        partial, 1);

    // ---- Readout from partials
    readout_kernel<<<NB, 128, 0, stream>>>(partial, Wr1, br1, Wr2, br2, out);
}

// Round 3
// 250.491 us; speedup vs baseline: 1.1838x; 1.0270x over previous
//
#include <hip/hip_runtime.h>
#include <hip/hip_bf16.h>

// Problem constants (match reference)
#define NB 128          // graphs
#define NN 512          // nodes per graph
#define NF 128          // feature dim
#define BN (NB*NN)      // 65536 total nodes
#define NE (BN*16)      // 1048576 edges
#define EPG 8192        // edges per graph (N*DEG_AVG)
#define WPR 16          // bitmap words per row (512 bits / 32)
#define ELLW 64         // ELL width (max padded degree)
#define QST 24          // poly w row stride in ushorts (48 B, 16-B aligned)
#define SST 72          // build-kernel ELL staging stride
#define WTS 136         // gemm Wt LDS stride in ushorts (272 B, 16-B aligned)

typedef short sh8 __attribute__((ext_vector_type(8)));
typedef float f32x4 __attribute__((ext_vector_type(4)));

static __device__ __forceinline__ unsigned short f2bf(float f) {
    unsigned u = __float_as_uint(f);
    u += 0x7fffu + ((u >> 16) & 1u);        // round-to-nearest-even
    return (unsigned short)(u >> 16);
}

// acc += bf16_low(pk)  /  acc += bf16_high(pk) via VOP3P dot2:
// D = S0.x*S1.x + S0.y*S1.y + S2 ; products exact (x1.0), +0 exact ->
// bitwise identical to shift+add, at half the instruction count.
#define DOT2LO(acc_, pk_, one_) \
    asm("v_dot2_f32_bf16 %0, %1, %2, %0" : "+v"(acc_) : "v"(pk_), "v"(one_))

// ---------------------------------------------------------------------------
// Fused adjacency + ELL build, one block per graph. LDS bitmap dedup.
// Rows ranked by degree; everything downstream lives in rank space.
// (unchanged)
// ---------------------------------------------------------------------------
__global__ __launch_bounds__(512) void build_ell_fused_kernel(
    const int* __restrict__ src, const int* __restrict__ dst,
    unsigned short* __restrict__ ell, int* __restrict__ ocnt,
    float* __restrict__ dinvr, int* __restrict__ perm)
{
    __shared__ unsigned bm[NN * WPR];   // 32 KB; later reused as ELL staging
    __shared__ int cs[NN];              // degree by row
    __shared__ int rdeg[NN];            // degree by rank
    __shared__ int irank[NN];           // row -> rank
    int g = blockIdx.x;
    int t = threadIdx.x;                // 0..511

    for (int i = t; i < NN * WPR; i += 512) bm[i] = 0u;
    __syncthreads();

    const int4* sg4 = (const int4*)(src + (size_t)g * EPG);
    const int4* dg4 = (const int4*)(dst + (size_t)g * EPG);
    for (int i = t; i < EPG / 4; i += 512) {
        int4 s4 = sg4[i];
        int4 d4 = dg4[i];
        int s, d;
        s = s4.x & (NN - 1); d = d4.x & (NN - 1);
        atomicOr(&bm[s * WPR + (d >> 5)], 1u << (d & 31));
        s = s4.y & (NN - 1); d = d4.y & (NN - 1);
        atomicOr(&bm[s * WPR + (d >> 5)], 1u << (d & 31));
        s = s4.z & (NN - 1); d = d4.z & (NN - 1);
        atomicOr(&bm[s * WPR + (d >> 5)], 1u << (d & 31));
        s = s4.w & (NN - 1); d = d4.w & (NN - 1);
        atomicOr(&bm[s * WPR + (d >> 5)], 1u << (d & 31));
    }
    __syncthreads();

    // extract this thread's row (row == t) into registers
    unsigned rw[WPR];
    #pragma unroll
    for (int w = 0; w < WPR; ++w) rw[w] = bm[t * WPR + w];
    int deg = 0;
    #pragma unroll
    for (int w = 0; w < WPR; ++w) deg += __popc(rw[w]);
    if (deg > ELLW) deg = ELLW;         // defensive
    cs[t] = deg;
    __syncthreads();                    // all bm reads done; cs visible

    // deterministic rank: ascending by (deg, row). LDS reads are broadcasts.
    int rk = 0;
    for (int i = 0; i < NN; ++i) {
        int di_ = cs[i];
        rk += (di_ < deg) || (di_ == deg && i < t);
    }
    rdeg[rk] = deg;
    irank[t] = rk;
    perm[(size_t)g * NN + rk] = t;
    dinvr[(size_t)g * NN + rk] = (deg > 0) ? rsqrtf((float)deg) : 0.0f;
    __syncthreads();

    if (t < NN / 8) {
        // ascending sort: oct max = last element of the oct
        int m = rdeg[t * 8 + 7];
        ocnt[(size_t)g * (NN / 8) + t] = (m + 3) & ~3;
    }

    // ELL staging (rank order, RANK-mapped entries) + coalesced writeout
    unsigned short* els = (unsigned short*)bm;
    for (int qtr = 0; qtr < 4; ++qtr) {
        if ((rk >> 7) == qtr) {
            unsigned short* er = &els[(rk & 127) * SST];
            int c = 0;
            #pragma unroll
            for (int w = 0; w < WPR; ++w) {
                unsigned bits = rw[w];
                while (bits) {
                    int j = __ffs(bits) - 1;
                    bits &= bits - 1;
                    if (c < ELLW) er[c] = (unsigned short)irank[w * 32 + j];
                    ++c;
                }
            }
            if (c > ELLW) c = ELLW;
            for (int p = c; p < ELLW; ++p) er[p] = (unsigned short)NN;
        }
        __syncthreads();
        unsigned short* outb = ell + ((size_t)g * NN + qtr * 128) * ELLW;
        for (int idx = t; idx < 1024; idx += 512) {
            int r2 = idx >> 3, sg2 = idx & 7;
            uint4 v = *(const uint4*)&els[r2 * SST + sg2 * 8];
            *(uint4*)&outb[(size_t)r2 * ELLW + sg2 * 8] = v;
        }
        __syncthreads();
    }
}

// ---------------------------------------------------------------------------
// Fused 3-hop poly conv in RANK space, one block per (graph, feature-EIGHTH).
// grid = 1024 blocks of 512 thr, 26.7 KB LDS.
// ANTITHETIC WAVE PAIRING (R3): ranks are degree-ascending; R2 gave wave wid
// the contiguous window [wid*64, wid*64+64), so wave 7 owned the 64 fattest
// rows (padded cnt ~24+32=56/thread vs avg 34) and every hop's __syncthreads
// made the other 7 waves wait for it (VALUBusy stuck ~38%). Now wave wid owns
// group A = [wid*32, +32) and its mirror B = [(15-wid)*32, +32): pair sums
// are ~constant (worst ~12+32=44) -> per-hop critical path -~20%.
// __launch_bounds__(512,4): min-waves=8 caused a 32-VGPR spill squeeze (R1).
// g = bid & 127 so all 8 blocks of a graph share one XCD's L2 for ELL.
// ---------------------------------------------------------------------------
__global__ __launch_bounds__(512, 4) void poly_fused_kernel(
    const float* __restrict__ xin,            // [BN, NF]
    float* __restrict__ accout,               // [BN, NF] rank space
    const unsigned short* __restrict__ ell,   // [BN][ELLW] rank entries
    const int* __restrict__ ocnt,             // [BN/8] padded oct counts
    const float* __restrict__ dinvr,          // [BN] rank-indexed
    const int* __restrict__ perm,             // [BN] rank -> row
    int permuteIn)
{
    extern __shared__ float lds[];
    unsigned short* w = (unsigned short*)lds;        // (NN+1) rows * QST
    float* dsh = lds + ((NN + 1) * QST * 2) / 4;     // NN floats

    int b = blockIdx.x;
    int g = b & 127;                     // graph (same-graph blocks -> same XCD)
    int q = b >> 7;                      // feature eighth (16 feats)
    int t = threadIdx.x;                 // 0..511
    int lane = t & 63;
    int wid  = t >> 6;                   // 0..7
    int slot = lane >> 1;                // 0..31
    int fb   = lane & 1;                 // 0..1 (8 feats each)

    unsigned one_lo = 0x00003F80u;       // bf16x2 (1.0, 0.0)
    unsigned one_hi = 0x3F800000u;       // bf16x2 (0.0, 1.0)

    if (t < NN) dsh[t] = dinvr[(size_t)g * NN + t];
    if (t < QST) w[NN * QST + t] = 0;    // zero sentinel row (bf16 0)

    // antithetic group bases: A = low-degree window, B = mirrored high-degree
    int rb[2];
    rb[0] = wid * 32;                    // groups 0..7   (ranks 0..255)
    rb[1] = (15 - wid) * 32;             // groups 15..8  (ranks 256..511)

    // input row for each group: perm'd for layer 1, identity (coalesced) else
    int px[2];
    if (permuteIn) {
        const int* pmg = perm + (size_t)g * NN;
        px[0] = pmg[rb[0] + slot];
        px[1] = pmg[rb[1] + slot];
    } else {
        px[0] = rb[0] + slot;
        px[1] = rb[1] + slot;
    }

    const float* xg = xin + (size_t)g * NN * NF + q * 16 + fb * 8;

    float acc[2][8];
    #pragma unroll
    for (int x = 0; x < 2; ++x) {
        int row = px[x];
        float4 a0 = *(const float4*)&xg[(size_t)row * NF];
        float4 a1 = *(const float4*)&xg[(size_t)row * NF + 4];
        acc[x][0] = a0.x; acc[x][1] = a0.y; acc[x][2] = a0.z; acc[x][3] = a0.w;
        acc[x][4] = a1.x; acc[x][5] = a1.y; acc[x][6] = a1.z; acc[x][7] = a1.w;
    }

    // per-group counts: max of the group's four oct counts (wave-uniform;
    // within a 32-rank window of the ascending sort the spread is small)
    const int* oc = ocnt + (size_t)g * (NN / 8);
    int co[2];
    #pragma unroll
    for (int x = 0; x < 2; ++x) {
        int o0 = (rb[x] >> 3);
        int m0 = max(oc[o0], oc[o0 + 1]);
        int m1 = max(oc[o0 + 2], oc[o0 + 3]);
        co[x] = __builtin_amdgcn_readfirstlane(max(m0, m1));
    }

    __syncthreads();                     // dsh + sentinel ready

    #pragma unroll
    for (int x = 0; x < 2; ++x) {
        int rr = rb[x] + slot;           // rank position
        float di = dsh[rr];
        unsigned pk[4];
        #pragma unroll
        for (int k = 0; k < 4; ++k) {
            unsigned lo = (unsigned)f2bf(di * acc[x][2 * k]);
            unsigned hi = (unsigned)f2bf(di * acc[x][2 * k + 1]);
            pk[k] = lo | (hi << 16);
        }
        *(uint4*)&w[rr * QST + fb * 8] = make_uint4(pk[0], pk[1], pk[2], pk[3]);
    }
    __syncthreads();                     // w init ready

    const unsigned short* elb0 =
        ell + ((size_t)g * NN + rb[0] + slot) * ELLW;
    const unsigned short* elb1 =
        ell + ((size_t)g * NN + rb[1] + slot) * ELLW;

    for (int hop = 0; hop < 3; ++hop) {
        float stage[2][8];
        ushort4 nq = *(const ushort4*)elb0;     // group A, batch 0
        #pragma unroll
        for (int x = 0; x < 2; ++x) {
            const unsigned short* el = x ? elb1 : elb0;
            int cnt = co[x];
            ushort4 cur = nq;
            if (x < 1)                   // prefetch group B's first batch
                nq = *(const ushort4*)elb1;
            float s[8];
            #pragma unroll
            for (int k = 0; k < 8; ++k) s[k] = 0.0f;
            for (int p = 0; p < cnt; p += 4) {
                ushort4 nxt = cur;
                if (p + 4 < cnt) nxt = *(const ushort4*)(el + p + 4);
                uint4 v0 = *(const uint4*)&w[(int)cur.x * QST + fb * 8];
                uint4 v1 = *(const uint4*)&w[(int)cur.y * QST + fb * 8];
                uint4 v2 = *(const uint4*)&w[(int)cur.z * QST + fb * 8];
                uint4 v3 = *(const uint4*)&w[(int)cur.w * QST + fb * 8];
                unsigned d[4][4] = {{v0.x, v0.y, v0.z, v0.w},
                                    {v1.x, v1.y, v1.z, v1.w},
                                    {v2.x, v2.y, v2.z, v2.w},
                                    {v3.x, v3.y, v3.z, v3.w}};
                #pragma unroll
                for (int n = 0; n < 4; ++n) {
                    #pragma unroll
                    for (int k = 0; k < 4; ++k) {
                        DOT2LO(s[2 * k],     d[n][k], one_lo);
                        DOT2LO(s[2 * k + 1], d[n][k], one_hi);
                    }
                }
                cur = nxt;
            }
            #pragma unroll
            for (int k = 0; k < 8; ++k) stage[x][k] = s[k];
        }
        __syncthreads();                 // all reads of old w done
        #pragma unroll
        for (int x = 0; x < 2; ++x) {
            int rr = rb[x] + slot;
            float di = dsh[rr];
            unsigned pk[4];
            #pragma unroll
            for (int k = 0; k < 4; ++k) {
                float zlo = di * stage[x][2 * k];
                float zhi = di * stage[x][2 * k + 1];
                acc[x][2 * k]     += zlo;
                acc[x][2 * k + 1] += zhi;
                unsigned lo = (unsigned)f2bf(di * zlo);
                unsigned hi = (unsigned)f2bf(di * zhi);
                pk[k] = lo | (hi << 16);
            }
            *(uint4*)&w[rr * QST + fb * 8] = make_uint4(pk[0], pk[1], pk[2], pk[3]);
        }
        __syncthreads();                 // new w visible
    }

    // coalesced write at rank positions
    float* og = accout + (size_t)g * NN * NF + q * 16 + fb * 8;
    #pragma unroll
    for (int x = 0; x < 2; ++x) {
        int rr = rb[x] + slot;
        *(float4*)&og[(size_t)rr * NF] =
            make_float4(acc[x][0], acc[x][1], acc[x][2], acc[x][3]);
        *(float4*)&og[(size_t)rr * NF + 4] =
            make_float4(acc[x][4], acc[x][5], acc[x][6], acc[x][7]);
    }
}

// ---------------------------------------------------------------------------
// MFMA bf16 GEMM: Y[65536,128] = relu(bf16(X) @ bf16(W) + b), optional fused
// deterministic mean-pool partials. (unchanged)
// ---------------------------------------------------------------------------
__global__ __launch_bounds__(256, 2) void gemm_bias_relu_kernel(
    const float* __restrict__ X, const float* __restrict__ W,
    const float* __restrict__ b, float* __restrict__ Y,
    float* __restrict__ partial, int fuse)
{
    __shared__ __align__(16) unsigned short Wt[NF * WTS];  // [n][k] bf16
    __shared__ float part[4 * NF];

    int t = threadIdx.x;

    // stage Wt = W^T in bf16
    for (int i = t; i < NF * NF / 4; i += 256) {
        int k = i >> 5;                 // W row
        int n4 = (i & 31) * 4;          // W col group
        float4 wv = ((const float4*)W)[i];
        Wt[(n4 + 0) * WTS + k] = f2bf(wv.x);
        Wt[(n4 + 1) * WTS + k] = f2bf(wv.y);
        Wt[(n4 + 2) * WTS + k] = f2bf(wv.z);
        Wt[(n4 + 3) * WTS + k] = f2bf(wv.w);
    }
    __syncthreads();

    int lane = t & 63;
    int wid  = t >> 6;                  // 0..3
    int quad = lane >> 4;               // 0..3
    int l16  = lane & 15;
    int rowA0 = blockIdx.x * 128 + wid * 32;

    // A fragments: af[m][kk], m in {0,1} (row halves), kk = K-step
    union { unsigned short u[8]; sh8 v; } af[2][4];
    #pragma unroll
    for (int m = 0; m < 2; ++m) {
        int r = rowA0 + m * 16 + l16;
        const float* xr = X + (size_t)r * NF + quad * 8;
        #pragma unroll
        for (int kk = 0; kk < 4; ++kk) {
            float4 x0 = *(const float4*)(xr + kk * 32);
            float4 x1 = *(const float4*)(xr + kk * 32 + 4);
            af[m][kk].u[0] = f2bf(x0.x); af[m][kk].u[1] = f2bf(x0.y);
            af[m][kk].u[2] = f2bf(x0.z); af[m][kk].u[3] = f2bf(x0.w);
            af[m][kk].u[4] = f2bf(x1.x); af[m][kk].u[5] = f2bf(x1.y);
            af[m][kk].u[6] = f2bf(x1.z); af[m][kk].u[7] = f2bf(x1.w);
        }
    }

    f32x4 acc[2][8];
    #pragma unroll
    for (int m = 0; m < 2; ++m)
        #pragma unroll
        for (int c = 0; c < 8; ++c) acc[m][c] = (f32x4){0.f, 0.f, 0.f, 0.f};

    #pragma unroll
    for (int c = 0; c < 8; ++c) {
        const unsigned short* wb = &Wt[(c * 16 + l16) * WTS + quad * 8];
        #pragma unroll
        for (int kk = 0; kk < 4; ++kk) {
            union { uint4 q; sh8 v; } bf_;
            bf_.q = *(const uint4*)(wb + kk * 32);
            acc[0][c] = __builtin_amdgcn_mfma_f32_16x16x32_bf16(
                af[0][kk].v, bf_.v, acc[0][c], 0, 0, 0);
            acc[1][c] = __builtin_amdgcn_mfma_f32_16x16x32_bf16(
                af[1][kk].v, bf_.v, acc[1][c], 0, 0, 0);
        }
    }

    float psum[8];
    #pragma unroll
    for (int c = 0; c < 8; ++c) psum[c] = 0.0f;

    #pragma unroll
    for (int c = 0; c < 8; ++c) {
        int col = c * 16 + l16;
        float bias = b[col];
        #pragma unroll
        for (int m = 0; m < 2; ++m) {
            #pragma unroll
            for (int reg = 0; reg < 4; ++reg) {
                int r = rowA0 + m * 16 + quad * 4 + reg;
                float v = fmaxf(acc[m][c][reg] + bias, 0.0f);
                Y[(size_t)r * NF + col] = v;
                psum[c] += v;
            }
        }
    }

    if (fuse) {
        // deterministic cross-quad reduction, then cross-wave LDS tree
        #pragma unroll
        for (int c = 0; c < 8; ++c) {
            float v = psum[c];
            v += __shfl_xor(v, 16);
            v += __shfl_xor(v, 32);
            if (lane < 16) part[wid * NF + c * 16 + lane] = v;
        }
        __syncthreads();
        if (t < NF) {
            float s = part[t] + part[NF + t] + part[2 * NF + t]
                    + part[3 * NF + t];
            partial[(size_t)blockIdx.x * NF + t] = s;
        }
    }
}

// ---------------------------------------------------------------------------
// Readout: per graph, mean-pool from gemm2 partials (4 blocks/graph) + MLP.
// ---------------------------------------------------------------------------
__global__ __launch_bounds__(128) void readout_kernel(
    const float* __restrict__ partial,   // [BN/128][NF]
    const float* __restrict__ Wr1, const float* __restrict__ br1,
    const float* __restrict__ Wr2, const float* __restrict__ br2,
    float* __restrict__ out)
{
    __shared__ float hsh[NF];
    __shared__ float r1[64];

    int g = blockIdx.x;
    int t = threadIdx.x;

    const float* pg = partial + (size_t)g * 4 * NF;
    float s = 0.0f;
    #pragma unroll
    for (int j = 0; j < 4; ++j) s += pg[j * NF + t];
    hsh[t] = s * (1.0f / (float)NN);
    __syncthreads();

    if (t < 64) {
        float a = br1[t];
        #pragma unroll 8
        for (int k = 0; k < NF; ++k) a += hsh[k] * Wr1[k * 64 + t];
        r1[t] = fmaxf(a, 0.0f);
    }
    __syncthreads();

    if (t < 64) {
        float v = r1[t] * Wr2[t];
        #pragma unroll
        for (int off = 32; off; off >>= 1) v += __shfl_down(v, off);
        if (t == 0) out[g] = v + br2[0];
    }
}

// ---------------------------------------------------------------------------
extern "C" void kernel_launch(void* const* d_in, const int* in_sizes, int n_in,
                              void* d_out, int out_size, void* d_ws, size_t ws_size,
                              hipStream_t stream)
{
    const float* X    = (const float*)d_in[0];
    // d_in[1] = batch (unused; nodes already grouped per graph)
    const int*   ei   = (const int*)d_in[2];
    const float* W1   = (const float*)d_in[3];
    const float* b1   = (const float*)d_in[4];
    const float* W2   = (const float*)d_in[5];
    const float* b2   = (const float*)d_in[6];
    const float* Wr1  = (const float*)d_in[7];
    const float* br1  = (const float*)d_in[8];
    const float* Wr2  = (const float*)d_in[9];
    const float* br2  = (const float*)d_in[10];
    float* out = (float*)d_out;

    const int* src = ei;
    const int* dst = ei + NE;

    // workspace layout
    char* ws = (char*)d_ws;
    float*          dinvr   = (float*)(ws);                          // 256 KB
    int*            ocnt    = (int*)(ws + (size_t)256 * 1024);       // 32 KB
    int*            perm    = (int*)(ws + (size_t)512 * 1024);       // 256 KB
    float*          partial = (float*)(ws + (size_t)768 * 1024);     // 256 KB
    unsigned short* ell     = (unsigned short*)(ws + (size_t)1024 * 1024); // 8 MB
    float*          buf0    = (float*)(ws + (size_t)16384 * 1024);   // 32 MB
    float*          buf1    = (float*)(ws + (size_t)49152 * 1024);   // 32 MB

    // fused adjacency+ELL build; rank-space outputs
    build_ell_fused_kernel<<<NB, 512, 0, stream>>>(src, dst, ell, ocnt, dinvr,
                                                   perm);

    // bf16 w rows (513 * 48 B) + dsh (512 floats) = 26,672 B
    const size_t LDSSZ = (size_t)(NN + 1) * QST * 2 + NN * 4;

    // ---- Layer 1 (X gathered via perm into rank space)
    poly_fused_kernel<<<NB * 8, 512, LDSSZ, stream>>>(X, buf0, ell, ocnt,
                                                      dinvr, perm, 1);
    gemm_bias_relu_kernel<<<BN / 128, 256, 0, stream>>>(buf0, W1, b1, buf1,
                                                        partial, 0);

    // ---- Layer 2 (all rank space, fully coalesced)
    poly_fused_kernel<<<NB * 8, 512, LDSSZ, stream>>>(buf1, buf0, ell, ocnt,
                                                      dinvr, perm, 0);
    gemm_bias_relu_kernel<<<BN / 128, 256, 0, stream>>>(buf0, W2, b2, buf1,
                                                        partial, 1);

    // ---- Readout from partials
    readout_kernel<<<NB, 128, 0, stream>>>(partial, Wr1, br1, Wr2, br2, out);
}